// Round 1
// baseline (4564.858 us; speedup 1.0000x reference)
//
#include <hip/hip_runtime.h>

#define N_NODES 100000
#define N_EDGES 3200000
#define C_CLUST 40
#define M_LAB   50000
#define IN_CH   128
#define HID     256
#define BN_EPS  1e-5f

// ---------------- graph preprocessing ----------------

__global__ void k_count(const int* __restrict__ dst, int* __restrict__ cnt) {
    int e = blockIdx.x * blockDim.x + threadIdx.x;
    if (e < N_EDGES) atomicAdd(&cnt[dst[e]], 1);
}

__global__ void k_dinv(const int* __restrict__ cnt, float* __restrict__ dinv) {
    int v = blockIdx.x * blockDim.x + threadIdx.x;
    if (v < N_NODES) dinv[v] = rsqrtf((float)cnt[v] + 1.0f);
}

// exclusive scan of counts -> row_ptr (3-phase)
__global__ void k_scan1(const int* __restrict__ cnt, int* __restrict__ row_ptr,
                        int* __restrict__ bsum) {
    __shared__ int s[256];
    int tid = threadIdx.x;
    int base = blockIdx.x * 1024 + tid * 4;
    int c0 = (base + 0 < N_NODES) ? cnt[base + 0] : 0;
    int c1 = (base + 1 < N_NODES) ? cnt[base + 1] : 0;
    int c2 = (base + 2 < N_NODES) ? cnt[base + 2] : 0;
    int c3 = (base + 3 < N_NODES) ? cnt[base + 3] : 0;
    int tsum = c0 + c1 + c2 + c3;
    s[tid] = tsum;
    __syncthreads();
    for (int off = 1; off < 256; off <<= 1) {
        int v = (tid >= off) ? s[tid - off] : 0;
        __syncthreads();
        s[tid] += v;
        __syncthreads();
    }
    int ex = s[tid] - tsum;
    if (base + 0 < N_NODES) row_ptr[base + 0] = ex;
    if (base + 1 < N_NODES) row_ptr[base + 1] = ex + c0;
    if (base + 2 < N_NODES) row_ptr[base + 2] = ex + c0 + c1;
    if (base + 3 < N_NODES) row_ptr[base + 3] = ex + c0 + c1 + c2;
    if (tid == 255) bsum[blockIdx.x] = s[255];
}

__global__ void k_scan2(const int* __restrict__ bsum, int* __restrict__ boff, int nb) {
    if (threadIdx.x == 0 && blockIdx.x == 0) {
        int run = 0;
        for (int i = 0; i < nb; i++) { boff[i] = run; run += bsum[i]; }
    }
}

__global__ void k_scan3(int* __restrict__ row_ptr, const int* __restrict__ boff,
                        int* __restrict__ cursor) {
    int tid = threadIdx.x;
    int base = blockIdx.x * 1024 + tid * 4;
    int off = boff[blockIdx.x];
#pragma unroll
    for (int i = 0; i < 4; i++) {
        int idx = base + i;
        if (idx < N_NODES) {
            int v = row_ptr[idx] + off;
            row_ptr[idx] = v;
            cursor[idx] = v;
        } else if (idx == N_NODES) {
            row_ptr[N_NODES] = N_EDGES;
        }
    }
}

__global__ void k_scatter(const int* __restrict__ src, const int* __restrict__ dst,
                          const float* __restrict__ dinv, int* __restrict__ cursor,
                          int* __restrict__ col, float* __restrict__ ew) {
    int e = blockIdx.x * blockDim.x + threadIdx.x;
    if (e < N_EDGES) {
        int s = src[e], d = dst[e];
        int pos = atomicAdd(&cursor[d], 1);
        col[pos] = s;
        ew[pos] = dinv[s] * dinv[d];
    }
}

// ---------------- GEMM: C[M,N] = A[M,K] @ B[K,N] (+ optional gather/LUT epilogue) ----------------
#define BM 128
#define BN 128
#define BK 16

__global__ __launch_bounds__(256) void k_gemm(
    const float* __restrict__ A, int lda,
    const float* __restrict__ B, int ldb,
    float* __restrict__ C, int ldc,
    int Mm, int Nn, int Kk,
    const int* __restrict__ gather,
    const int* __restrict__ assign,
    const float* __restrict__ lut) {
    __shared__ float As[BK * BM];
    __shared__ float Bs[BK * BN];
    int tid = threadIdx.x;
    int tx = tid & 15, ty = tid >> 4;
    int bm = blockIdx.x * BM, bn = blockIdx.y * BN;

    float acc[8][8];
#pragma unroll
    for (int i = 0; i < 8; i++)
#pragma unroll
        for (int j = 0; j < 8; j++) acc[i][j] = 0.f;

    for (int k0 = 0; k0 < Kk; k0 += BK) {
        // stage A tile (transposed into As[k][m])
#pragma unroll
        for (int L0 = 0; L0 < 2; L0++) {
            int L = tid + L0 * 256;
            int r = L >> 2, kq = L & 3;
            int row = bm + r;
            float4 av = make_float4(0.f, 0.f, 0.f, 0.f);
            if (row < Mm) {
                int arow = gather ? gather[row] : row;
                av = *(const float4*)&A[(size_t)arow * lda + k0 + kq * 4];
            }
            As[(kq * 4 + 0) * BM + r] = av.x;
            As[(kq * 4 + 1) * BM + r] = av.y;
            As[(kq * 4 + 2) * BM + r] = av.z;
            As[(kq * 4 + 3) * BM + r] = av.w;
        }
        // stage B tile
#pragma unroll
        for (int L0 = 0; L0 < 2; L0++) {
            int L = tid + L0 * 256;
            int kr = L >> 5, cq = L & 31;
            int colg = bn + cq * 4;
            float4 bv = make_float4(0.f, 0.f, 0.f, 0.f);
            if (colg < Nn) bv = *(const float4*)&B[(size_t)(k0 + kr) * ldb + colg];
            *(float4*)&Bs[kr * BN + cq * 4] = bv;
        }
        __syncthreads();
#pragma unroll
        for (int kk = 0; kk < BK; kk++) {
            float a[8], b[8];
            *(float4*)&a[0] = *(const float4*)&As[kk * BM + ty * 8];
            *(float4*)&a[4] = *(const float4*)&As[kk * BM + ty * 8 + 4];
            *(float4*)&b[0] = *(const float4*)&Bs[kk * BN + tx * 8];
            *(float4*)&b[4] = *(const float4*)&Bs[kk * BN + tx * 8 + 4];
#pragma unroll
            for (int i = 0; i < 8; i++)
#pragma unroll
                for (int j = 0; j < 8; j++) acc[i][j] = fmaf(a[i], b[j], acc[i][j]);
        }
        __syncthreads();
    }

#pragma unroll
    for (int i = 0; i < 8; i++) {
        int row = bm + ty * 8 + i;
        if (row >= Mm) continue;
        float* crow = C + (size_t)row * ldc;
        const float* lrow = lut ? (lut + (size_t)assign[row] * ldc) : nullptr;
#pragma unroll
        for (int j = 0; j < 8; j += 4) {
            int colg = bn + tx * 8 + j;
            if (colg < Nn) {
                float4 v;
                v.x = acc[i][j + 0]; v.y = acc[i][j + 1];
                v.z = acc[i][j + 2]; v.w = acc[i][j + 3];
                if (lrow) {
                    v.x += lrow[colg + 0]; v.y += lrow[colg + 1];
                    v.z += lrow[colg + 2]; v.w += lrow[colg + 3];
                }
                *(float4*)&crow[colg] = v;
            }
        }
    }
}

// ---------------- aggregation: out[v] = sum_e w_e*T[src_e] + dinv[v]^2*T[v] + b ----------------

__global__ __launch_bounds__(256) void k_agg(
    const float* __restrict__ T, const int* __restrict__ row_ptr,
    const int* __restrict__ col, const float* __restrict__ ew,
    const float* __restrict__ dinv, const float* __restrict__ bias,
    float* __restrict__ out) {
    int wid = threadIdx.x >> 6, lane = threadIdx.x & 63;
    int v = blockIdx.x * 4 + wid;
    if (v >= N_NODES) return;
    int beg = row_ptr[v], end = row_ptr[v + 1];
    int c4 = lane * 4;
    float4 acc = make_float4(0.f, 0.f, 0.f, 0.f);
    int j = beg;
    for (; j + 4 <= end; j += 4) {
        int s0 = col[j], s1 = col[j + 1], s2 = col[j + 2], s3 = col[j + 3];
        float w0 = ew[j], w1 = ew[j + 1], w2 = ew[j + 2], w3 = ew[j + 3];
        float4 t0 = *(const float4*)&T[(size_t)s0 * HID + c4];
        float4 t1 = *(const float4*)&T[(size_t)s1 * HID + c4];
        float4 t2 = *(const float4*)&T[(size_t)s2 * HID + c4];
        float4 t3 = *(const float4*)&T[(size_t)s3 * HID + c4];
        acc.x = fmaf(w0, t0.x, acc.x); acc.y = fmaf(w0, t0.y, acc.y);
        acc.z = fmaf(w0, t0.z, acc.z); acc.w = fmaf(w0, t0.w, acc.w);
        acc.x = fmaf(w1, t1.x, acc.x); acc.y = fmaf(w1, t1.y, acc.y);
        acc.z = fmaf(w1, t1.z, acc.z); acc.w = fmaf(w1, t1.w, acc.w);
        acc.x = fmaf(w2, t2.x, acc.x); acc.y = fmaf(w2, t2.y, acc.y);
        acc.z = fmaf(w2, t2.z, acc.z); acc.w = fmaf(w2, t2.w, acc.w);
        acc.x = fmaf(w3, t3.x, acc.x); acc.y = fmaf(w3, t3.y, acc.y);
        acc.z = fmaf(w3, t3.z, acc.z); acc.w = fmaf(w3, t3.w, acc.w);
    }
    for (; j < end; j++) {
        int s = col[j];
        float w = ew[j];
        float4 t = *(const float4*)&T[(size_t)s * HID + c4];
        acc.x = fmaf(w, t.x, acc.x); acc.y = fmaf(w, t.y, acc.y);
        acc.z = fmaf(w, t.z, acc.z); acc.w = fmaf(w, t.w, acc.w);
    }
    float dv = dinv[v];
    float sw = dv * dv;
    float4 tv = *(const float4*)&T[(size_t)v * HID + c4];
    float4 bb = *(const float4*)&bias[c4];
    acc.x = fmaf(sw, tv.x, acc.x) + bb.x;
    acc.y = fmaf(sw, tv.y, acc.y) + bb.y;
    acc.z = fmaf(sw, tv.z, acc.z) + bb.z;
    acc.w = fmaf(sw, tv.w, acc.w) + bb.w;
    *(float4*)&out[(size_t)v * HID + c4] = acc;
}

// ---------------- batch norm ----------------

__global__ void k_bnstats(const float* __restrict__ H, float* __restrict__ stats) {
    int c = threadIdx.x;
    float s = 0.f, q = 0.f;
    for (int r = blockIdx.x; r < N_NODES; r += gridDim.x) {
        float v = H[(size_t)r * HID + c];
        s += v;
        q += v * v;
    }
    atomicAdd(&stats[c], s);
    atomicAdd(&stats[HID + c], q);
}

__global__ void k_bnfin(const float* __restrict__ stats, const float* __restrict__ g,
                        const float* __restrict__ be, float* __restrict__ scsh) {
    int c = threadIdx.x;
    float mean = stats[c] * (1.0f / N_NODES);
    float var = stats[HID + c] * (1.0f / N_NODES) - mean * mean;
    float sc = g[c] * rsqrtf(var + BN_EPS);
    scsh[c] = sc;
    scsh[HID + c] = be[c] - mean * sc;
}

__global__ void k_bnapply(float* __restrict__ H, const float* __restrict__ scsh) {
    __shared__ float sc[HID], sh[HID];
    int tid = threadIdx.x;
    sc[tid] = scsh[tid];
    sh[tid] = scsh[HID + tid];
    __syncthreads();
    int total = N_NODES * (HID / 4);
    for (int i = blockIdx.x * blockDim.x + tid; i < total; i += gridDim.x * blockDim.x) {
        int cb = (i & 63) * 4;
        float4 v = *(float4*)((float*)H + (size_t)i * 4);
        v.x = fmaxf(fmaf(v.x, sc[cb + 0], sh[cb + 0]), 0.f);
        v.y = fmaxf(fmaf(v.y, sc[cb + 1], sh[cb + 1]), 0.f);
        v.z = fmaxf(fmaf(v.z, sc[cb + 2], sh[cb + 2]), 0.f);
        v.w = fmaxf(fmaf(v.w, sc[cb + 3], sh[cb + 3]), 0.f);
        *(float4*)((float*)H + (size_t)i * 4) = v;
    }
}

// ---------------- cluster pooling ----------------

__global__ void k_assign(const float* __restrict__ cid, int* __restrict__ assign,
                         float* __restrict__ ccount) {
    int i = blockIdx.x * blockDim.x + threadIdx.x;
    if (i < M_LAB) {
        const float* row = cid + (size_t)i * C_CLUST;
        float best = row[0];
        int bi = 0;
        for (int j = 1; j < C_CLUST; j++) {
            float v = row[j];
            if (v > best) { best = v; bi = j; }
        }
        assign[i] = bi;
        atomicAdd(&ccount[bi], 1.0f);
    }
}

__global__ __launch_bounds__(256) void k_csum(const float* __restrict__ H,
                                              const int* __restrict__ cindex,
                                              const int* __restrict__ assign,
                                              float* __restrict__ cfsum) {
    __shared__ float lacc[C_CLUST * HID];  // 40 KB
    int tid = threadIdx.x;
    for (int k = tid; k < C_CLUST * HID; k += 256) lacc[k] = 0.f;
    __syncthreads();
    int wid = tid >> 6, lane = tid & 63;
    int base = blockIdx.x * 512;
    int endr = min(base + 512, M_LAB);
    for (int r = base + wid; r < endr; r += 4) {
        int c = assign[r];
        int idx = cindex[r];
        float4 t = *(const float4*)&H[(size_t)idx * HID + lane * 4];
        float* dstp = &lacc[c * HID + lane * 4];
        atomicAdd(&dstp[0], t.x);
        atomicAdd(&dstp[1], t.y);
        atomicAdd(&dstp[2], t.z);
        atomicAdd(&dstp[3], t.w);
    }
    __syncthreads();
    for (int k = tid; k < C_CLUST * HID; k += 256) {
        float v = lacc[k];
        if (v != 0.f) atomicAdd(&cfsum[k], v);
    }
}

__global__ void k_cfin(const float* __restrict__ cfsum, const float* __restrict__ ccount,
                       float* __restrict__ cf) {
    int c = blockIdx.x, k = threadIdx.x;
    cf[c * HID + k] = cfsum[c * HID + k] / ccount[c];
}

// LUT1[c][j] = fcb[j] + sum_k cf[c][k]*fcW[(k+256)*1600+j]   (x1 contribution, first half)
// LUT2[c][j] = fcb[j] + sum_k cf[c][k]*fcW[k*1600+j]         (x1 contribution, second half)
__global__ void k_lut(const float* __restrict__ cf, const float* __restrict__ fcW,
                      const float* __restrict__ fcb, float* __restrict__ lut1,
                      float* __restrict__ lut2) {
    __shared__ float scf[HID];
    int c = blockIdx.y;
    int tid = threadIdx.x;
    scf[tid] = cf[c * HID + tid];
    __syncthreads();
    int j = blockIdx.x * 256 + tid;
    if (j < C_CLUST * C_CLUST) {
        float a1 = fcb[j], a2 = fcb[j];
        for (int k = 0; k < HID; k++) {
            float cv = scf[k];
            a2 = fmaf(cv, fcW[(size_t)k * 1600 + j], a2);
            a1 = fmaf(cv, fcW[(size_t)(k + HID) * 1600 + j], a1);
        }
        lut1[c * 1600 + j] = a1;
        lut2[c * 1600 + j] = a2;
    }
}

// ---------------- launch ----------------

extern "C" void kernel_launch(void* const* d_in, const int* in_sizes, int n_in,
                              void* d_out, int out_size, void* d_ws, size_t ws_size,
                              hipStream_t stream) {
    const float* x    = (const float*)d_in[0];
    const int*   ei   = (const int*)d_in[1];
    const float* cid  = (const float*)d_in[2];
    const int*   cidx = (const int*)d_in[3];
    const float* W0   = (const float*)d_in[4];
    const float* b0   = (const float*)d_in[5];
    const float* g0   = (const float*)d_in[6];
    const float* be0  = (const float*)d_in[7];
    const float* W1   = (const float*)d_in[8];
    const float* b1   = (const float*)d_in[9];
    const float* g1   = (const float*)d_in[10];
    const float* be1  = (const float*)d_in[11];
    const float* W2   = (const float*)d_in[12];
    const float* b2   = (const float*)d_in[13];
    const float* g2   = (const float*)d_in[14];
    const float* be2  = (const float*)d_in[15];
    const float* fcW  = (const float*)d_in[16];
    const float* fcb  = (const float*)d_in[17];
    float* out = (float*)d_out;

    char* ws = (char*)d_ws;
    size_t off = 0;
    auto alloc = [&](size_t b) -> char* {
        char* p = ws + off;
        off += (b + 255) & ~(size_t)255;
        return p;
    };
    float* H1     = (float*)alloc((size_t)N_NODES * HID * 4);   // 102.4 MB
    float* H2     = (float*)alloc((size_t)N_NODES * HID * 4);   // 102.4 MB
    int*   col    = (int*)alloc((size_t)N_EDGES * 4);
    float* ew     = (float*)alloc((size_t)N_EDGES * 4);
    int*   counts = (int*)alloc((size_t)N_NODES * 4);
    float* dinv   = (float*)alloc((size_t)N_NODES * 4);
    int*   rowptr = (int*)alloc((size_t)(N_NODES + 1) * 4);
    int*   cursor = (int*)alloc((size_t)N_NODES * 4);
    int*   bsum   = (int*)alloc(512);
    int*   boff   = (int*)alloc(512);
    float* stats  = (float*)alloc(2 * HID * 4);
    float* scsh   = (float*)alloc(2 * HID * 4);
    int*   assign = (int*)alloc((size_t)M_LAB * 4);
    float* ccount = (float*)alloc(256);
    float* cfsum  = (float*)alloc((size_t)C_CLUST * HID * 4);
    float* cf     = (float*)alloc((size_t)C_CLUST * HID * 4);
    float* lut1   = (float*)alloc((size_t)C_CLUST * 1600 * 4);
    float* lut2   = (float*)alloc((size_t)C_CLUST * 1600 * 4);
    (void)ws_size; (void)in_sizes; (void)n_in; (void)out_size;

    const int* src = ei;
    const int* dst = ei + N_EDGES;

    // graph preprocessing -> CSR
    hipMemsetAsync(counts, 0, (size_t)N_NODES * 4, stream);
    k_count<<<(N_EDGES + 255) / 256, 256, 0, stream>>>(dst, counts);
    k_dinv<<<(N_NODES + 255) / 256, 256, 0, stream>>>(counts, dinv);
    k_scan1<<<98, 256, 0, stream>>>(counts, rowptr, bsum);
    k_scan2<<<1, 64, 0, stream>>>(bsum, boff, 98);
    k_scan3<<<98, 256, 0, stream>>>(rowptr, boff, cursor);
    k_scatter<<<(N_EDGES + 255) / 256, 256, 0, stream>>>(src, dst, dinv, cursor, col, ew);

    // 3 GCN layers
    const float* hin = x;
    int K = IN_CH;
    const float* Ws[3] = {W0, W1, W2};
    const float* bs[3] = {b0, b1, b2};
    const float* gs[3] = {g0, g1, g2};
    const float* bes[3] = {be0, be1, be2};
    for (int l = 0; l < 3; l++) {
        dim3 gg((N_NODES + BM - 1) / BM, HID / BN);
        k_gemm<<<gg, 256, 0, stream>>>(hin, K, Ws[l], HID, H2, HID, N_NODES, HID, K,
                                       nullptr, nullptr, nullptr);
        k_agg<<<N_NODES / 4, 256, 0, stream>>>(H2, rowptr, col, ew, dinv, bs[l], H1);
        hipMemsetAsync(stats, 0, 2 * HID * 4, stream);
        k_bnstats<<<512, 256, 0, stream>>>(H1, stats);
        k_bnfin<<<1, 256, 0, stream>>>(stats, gs[l], bes[l], scsh);
        k_bnapply<<<2048, 256, 0, stream>>>(H1, scsh);
        hin = H1;
        K = HID;
    }

    // cluster pooling
    hipMemsetAsync(ccount, 0, 256, stream);
    hipMemsetAsync(cfsum, 0, (size_t)C_CLUST * HID * 4, stream);
    k_assign<<<(M_LAB + 255) / 256, 256, 0, stream>>>(cid, assign, ccount);
    k_csum<<<(M_LAB + 511) / 512, 256, 0, stream>>>(H1, cidx, assign, cfsum);
    k_cfin<<<C_CLUST, HID, 0, stream>>>(cfsum, ccount, cf);
    k_lut<<<dim3(7, C_CLUST), 256, 0, stream>>>(cf, fcW, fcb, lut1, lut2);

    // final FC: out[0:M]   = xs @ fcW_top + LUT1[assign]
    //           out[M:2M]  = xs @ fcW_bot + LUT2[assign]
    dim3 gf((M_LAB + BM - 1) / BM, (1600 + BN - 1) / BN);
    k_gemm<<<gf, 256, 0, stream>>>(H1, HID, fcW, 1600, out, 1600, M_LAB, 1600, HID,
                                   cidx, assign, lut1);
    k_gemm<<<gf, 256, 0, stream>>>(H1, HID, fcW + (size_t)HID * 1600, 1600,
                                   out + (size_t)M_LAB * 1600, 1600, M_LAB, 1600, HID,
                                   cidx, assign, lut2);
}